// Round 1
// baseline (768.197 us; speedup 1.0000x reference)
//
#include <hip/hip_runtime.h>
#include <math.h>

// Problem dims (fixed by the reference)
#define B_ 8
#define L_ 8192
#define H_ 128
#define N_ 32
#define C_ 128   // number of chunks along L
#define T_ 64    // chunk length (C_*T_ == L_)

// ---------------------------------------------------------------------------
// ws layout (bytes):
//   cwc4 : float4[H_*N_]          @ 0         (wr,wi,coef_r,coef_i)   64 KB
//   wT2  : float2[H_*N_]          @ 65536     (w^T)                   32 KB
//   Wt   : float [H_*256]         @ 98304     (out_w transposed)     128 KB
//   U    : float [B_*H_*L_]       @ 229376    (u, overwritten by gy)  32 MB
//   E    : float2[B_*H_*C_*N_]    @ 33783808  (chunk sums -> states)  32 MB
// total ~64.3 MB
// ---------------------------------------------------------------------------

__device__ __forceinline__ float gelu_tanh(float y) {
    // jax.nn.gelu default (approximate=True)
    float t = 0.7978845608028654f * fmaf(0.044715f, y * y * y, y);
    float e = __expf(2.f * t);
    float th = 1.f - __fdividef(2.f, e + 1.f);
    return 0.5f * y * (1.f + th);
}

// ---------------------------------------------------------------------------
// Kernel 1: constants + out_w transpose + out init + encoder
// blocks 0..15: per-(h,n) constants; 16..143: Wt; 144: out init; 145..400: enc
// ---------------------------------------------------------------------------
__global__ __launch_bounds__(256) void k_setup(
    const float* __restrict__ x, const float* __restrict__ enc_w,
    const float* __restrict__ enc_b, const float* __restrict__ log_dt,
    const float* __restrict__ log_A_real, const float* __restrict__ A_imag,
    const float* __restrict__ C_re, const float* __restrict__ C_im,
    const float* __restrict__ out_w, const float* __restrict__ dec_b,
    float* __restrict__ out, float4* __restrict__ cwc4,
    float2* __restrict__ wT2, float* __restrict__ Wt, float* __restrict__ U)
{
    int blk = blockIdx.x;
    int tid = threadIdx.x;
    if (blk < 16) {
        int idx = blk * 256 + tid;            // (h,n), 0..4095
        int h = idx >> 5;
        float dt = expf(log_dt[h]);
        float Ar = -expf(log_A_real[idx]);
        float Ai = A_imag[idx];
        float ar = dt * Ar, ai = dt * Ai;
        float er = expf(ar);
        float wr = er * cosf(ai), wi = er * sinf(ai);
        // coef = C * (exp(dtA)-1)/A
        float numr = wr - 1.f, numi = wi;
        float inv = 1.f / (Ar * Ar + Ai * Ai);
        float qr = (numr * Ar + numi * Ai) * inv;
        float qi = (numi * Ar - numr * Ai) * inv;
        float cr = C_re[idx] * qr - C_im[idx] * qi;
        float ci = C_re[idx] * qi + C_im[idx] * qr;
        cwc4[idx] = make_float4(wr, wi, cr, ci);
        float erT = expf(ar * (float)T_);
        wT2[idx] = make_float2(erT * cosf(ai * (float)T_), erT * sinf(ai * (float)T_));
    } else if (blk < 144) {
        int idx = (blk - 16) * 256 + tid;     // 0..32767  Wt[h][g] = out_w[g][h]
        int h = idx >> 8, g = idx & 255;
        Wt[idx] = out_w[g * H_ + h];
    } else if (blk == 144) {
        if (tid < B_) out[tid] = dec_b[0];
    } else {
        int p = (blk - 145) * 256 + tid;      // 0..65535 = b*L + l
        int b = p >> 13, l = p & (L_ - 1);
        float2 xv = ((const float2*)x)[p];
        for (int h = 0; h < H_; ++h) {
            U[(b * H_ + h) * L_ + l] =
                fmaf(xv.x, enc_w[h], fmaf(xv.y, enc_w[H_ + h], enc_b[h]));
        }
    }
}

// ---------------------------------------------------------------------------
// Kernel 2: per-chunk Horner sums  E_c = sum_{j<T} w^{T-1-j} u[c*T+j]
// thread = (b,h,n,c), n fastest (coalesced E write, broadcast u read)
// ---------------------------------------------------------------------------
__global__ __launch_bounds__(256) void k_chunk(
    const float4* __restrict__ cwc4, const float* __restrict__ U,
    float2* __restrict__ E)
{
    int g = blockIdx.x * 256 + threadIdx.x;
    int n = g & 31;
    int c = (g >> 5) & (C_ - 1);
    int h = (g >> 12) & (H_ - 1);
    int b = g >> 19;
    float4 cw = cwc4[(h << 5) + n];
    float wr = cw.x, wi = cw.y;
    const float4* up = (const float4*)(U + (b * H_ + h) * L_ + c * T_);
    float Er = 0.f, Ei = 0.f;
#pragma unroll
    for (int t4 = 0; t4 < T_ / 4; ++t4) {
        float4 uv = up[t4];
        float u0, nr;
        u0 = uv.x; nr = fmaf(wr, Er, fmaf(-wi, Ei, u0)); Ei = fmaf(wr, Ei, wi * Er); Er = nr;
        u0 = uv.y; nr = fmaf(wr, Er, fmaf(-wi, Ei, u0)); Ei = fmaf(wr, Ei, wi * Er); Er = nr;
        u0 = uv.z; nr = fmaf(wr, Er, fmaf(-wi, Ei, u0)); Ei = fmaf(wr, Ei, wi * Er); Er = nr;
        u0 = uv.w; nr = fmaf(wr, Er, fmaf(-wi, Ei, u0)); Ei = fmaf(wr, Ei, wi * Er); Er = nr;
    }
    E[((b * H_ + h) * C_ + c) * N_ + n] = make_float2(Er, Ei);
}

// ---------------------------------------------------------------------------
// Kernel 3: sequential scan over chunks, in place:
//   S_in[0]=0 ; S_in[c] = w^T * S_in[c-1] + E[c-1]   (written into E slot c)
// ---------------------------------------------------------------------------
__global__ __launch_bounds__(256) void k_scan(
    const float2* __restrict__ wT2, float2* __restrict__ E)
{
    int g = blockIdx.x * 256 + threadIdx.x;   // 0..32767 = (b,h,n)
    int n = g & 31;
    int h = (g >> 5) & (H_ - 1);
    int b = g >> 12;
    float2 wT = wT2[(h << 5) + n];
    float2* base = E + (size_t)((b * H_ + h) * C_) * N_ + n;
    float Sr = 0.f, Si = 0.f;
    for (int c = 0; c < C_; ++c) {
        float2 e = base[(size_t)c * N_];
        base[(size_t)c * N_] = make_float2(Sr, Si);
        float nr = fmaf(wT.x, Sr, fmaf(-wT.y, Si, e.x));
        Si = fmaf(wT.x, Si, fmaf(wT.y, Sr, e.y));
        Sr = nr;
    }
}

// ---------------------------------------------------------------------------
// Kernel 4: intra-chunk recurrence with incoming state; skip + GELU; write gy
// in place over U. thread = (b,h,c); 32 complex states live in VGPRs.
// ---------------------------------------------------------------------------
__global__ __launch_bounds__(256, 2) void k_intra(
    const float4* __restrict__ cwc4, const float2* __restrict__ E,
    const float* __restrict__ Dp, float* __restrict__ U)
{
    __shared__ float4 cwL[64];                // 2 h's worth of (w,coef)
    int blk = blockIdx.x;
    int tid = threadIdx.x;
    int b = blk >> 6, hp = blk & 63;
    int hl = tid >> 7, c = tid & 127;
    int h = hp * 2 + hl;
    if (tid < 64) cwL[tid] = cwc4[hp * 64 + tid];
    __syncthreads();

    float sr[N_], si[N_];
    const float4* sp = (const float4*)(E + (size_t)((b * H_ + h) * C_ + c) * N_);
#pragma unroll
    for (int n2 = 0; n2 < 16; ++n2) {
        float4 s = sp[n2];
        sr[2 * n2] = s.x; si[2 * n2] = s.y;
        sr[2 * n2 + 1] = s.z; si[2 * n2 + 1] = s.w;
    }
    float Dh = Dp[h];
    float* uy = U + (b * H_ + h) * L_ + c * T_;
    const float4* cb = cwL + (hl << 5);

#pragma unroll 1
    for (int t4 = 0; t4 < T_ / 4; ++t4) {
        float4 uv = ((const float4*)uy)[t4];
        float4 ov;
#pragma unroll
        for (int k = 0; k < 4; ++k) {
            float uu = ((const float*)&uv)[k];
            float p = 0.f;
#pragma unroll
            for (int n = 0; n < N_; ++n) {
                float4 q = cb[n];
                float nr = fmaf(q.x, sr[n], fmaf(-q.y, si[n], uu));
                float ni = fmaf(q.x, si[n], q.y * sr[n]);
                sr[n] = nr; si[n] = ni;
                p = fmaf(q.z, nr, fmaf(-q.w, ni, p));
            }
            float y = fmaf(Dh, uu, 2.f * p);
            ((float*)&ov)[k] = gelu_tanh(y);
        }
        ((float4*)uy)[t4] = ov;
    }
}

// ---------------------------------------------------------------------------
// Kernel 5: pointwise GLU mix + pooled decode.
// block = (b, 64-l tile); wave w covers g in [32w,32w+32); lane = l.
// W chunk staged in LDS (broadcast reads); gy read coalesced from global.
// ---------------------------------------------------------------------------
__global__ __launch_bounds__(256) void k_mix(
    const float* __restrict__ Wt, const float* __restrict__ gy,
    const float* __restrict__ out_b, const float* __restrict__ dec_w,
    float* __restrict__ out)
{
    __shared__ float Wl[32][256];
    __shared__ float red[4];
    int blk = blockIdx.x;
    int b = blk >> 7, lt = blk & 127;
    int l0 = lt * 64;
    int tid = threadIdx.x;
    int wq = tid >> 6, lane = tid & 63;
    int g0 = wq * 32;

    float aa[32], ag[32];
#pragma unroll
    for (int j = 0; j < 32; ++j) { aa[j] = 0.f; ag[j] = 0.f; }

    for (int hc = 0; hc < 4; ++hc) {
        __syncthreads();
        const float4* src = (const float4*)(Wt + hc * 32 * 256);
        float4* dst = (float4*)(&Wl[0][0]);
#pragma unroll
        for (int r = 0; r < 8; ++r) dst[r * 256 + tid] = src[r * 256 + tid];
        __syncthreads();
        const float* gp = gy + (b * H_ + hc * 32) * L_ + l0 + lane;
#pragma unroll 2
        for (int h = 0; h < 32; ++h) {
            float v = gp[(size_t)h * L_];
#pragma unroll
            for (int j4 = 0; j4 < 8; ++j4) {
                float4 wa = *(const float4*)&Wl[h][g0 + j4 * 4];
                float4 wg = *(const float4*)&Wl[h][128 + g0 + j4 * 4];
                aa[j4 * 4 + 0] = fmaf(wa.x, v, aa[j4 * 4 + 0]);
                aa[j4 * 4 + 1] = fmaf(wa.y, v, aa[j4 * 4 + 1]);
                aa[j4 * 4 + 2] = fmaf(wa.z, v, aa[j4 * 4 + 2]);
                aa[j4 * 4 + 3] = fmaf(wa.w, v, aa[j4 * 4 + 3]);
                ag[j4 * 4 + 0] = fmaf(wg.x, v, ag[j4 * 4 + 0]);
                ag[j4 * 4 + 1] = fmaf(wg.y, v, ag[j4 * 4 + 1]);
                ag[j4 * 4 + 2] = fmaf(wg.z, v, ag[j4 * 4 + 2]);
                ag[j4 * 4 + 3] = fmaf(wg.w, v, ag[j4 * 4 + 3]);
            }
        }
    }
    // GLU + dec_w dot for this thread's (l, g-range)
    float s = 0.f;
#pragma unroll
    for (int j = 0; j < 32; ++j) {
        int g = g0 + j;
        float za = aa[j] + out_b[g];
        float zg = ag[j] + out_b[128 + g];
        float sig = __fdividef(1.f, 1.f + __expf(-zg));
        s = fmaf(dec_w[g], za * sig, s);
    }
#pragma unroll
    for (int off = 32; off; off >>= 1) s += __shfl_down(s, off, 64);
    if (lane == 0) red[wq] = s;
    __syncthreads();
    if (tid == 0) {
        float tot = (red[0] + red[1] + red[2] + red[3]) * (1.0f / (float)L_);
        atomicAdd(out + b, tot);
    }
}

// ---------------------------------------------------------------------------
extern "C" void kernel_launch(void* const* d_in, const int* in_sizes, int n_in,
                              void* d_out, int out_size, void* d_ws, size_t ws_size,
                              hipStream_t stream)
{
    const float* x         = (const float*)d_in[0];
    const float* enc_w     = (const float*)d_in[1];
    const float* enc_b     = (const float*)d_in[2];
    const float* log_dt    = (const float*)d_in[3];
    const float* log_A_real= (const float*)d_in[4];
    const float* A_imag    = (const float*)d_in[5];
    const float* C_re      = (const float*)d_in[6];
    const float* C_im      = (const float*)d_in[7];
    const float* Dp        = (const float*)d_in[8];
    const float* out_w     = (const float*)d_in[9];
    const float* out_b     = (const float*)d_in[10];
    const float* dec_w     = (const float*)d_in[11];
    const float* dec_b     = (const float*)d_in[12];
    float* out = (float*)d_out;

    char* ws = (char*)d_ws;
    float4* cwc4 = (float4*)(ws);
    float2* wT2  = (float2*)(ws + 65536);
    float*  Wt   = (float*)(ws + 98304);
    float*  U    = (float*)(ws + 229376);
    float2* E    = (float2*)(ws + 33783808);

    k_setup<<<401, 256, 0, stream>>>(x, enc_w, enc_b, log_dt, log_A_real, A_imag,
                                     C_re, C_im, out_w, dec_b, out, cwc4, wT2, Wt, U);
    k_chunk<<<16384, 256, 0, stream>>>(cwc4, U, E);
    k_scan<<<128, 256, 0, stream>>>(wT2, E);
    k_intra<<<512, 256, 0, stream>>>(cwc4, E, Dp, U);
    k_mix<<<1024, 256, 0, stream>>>(Wt, U, out_b, dec_w, out);
}

// Round 2
// 287.992 us; speedup vs baseline: 2.6674x; 2.6674x over previous
//
#include <hip/hip_runtime.h>
#include <math.h>

// Problem dims (fixed by the reference)
#define B_ 8
#define L_ 8192
#define H_ 128
#define N_ 32
#define C_ 128   // chunks along L (= threads per k_s4d block)
#define T_ 64    // chunk length (C_*T_ == L_)

// ws layout: Wt float[H_*256] @ 0 (128 KB); gy float[B_*H_*L_] @ 131072 (32 MB)
// gy layout per (b,h): index t*C_ + c  (a fixed permutation of l = c*T_+t;
// k_mix is pointwise-over-l + mean-pool, so any fixed permutation is fine)

__device__ __forceinline__ float gelu_tanh(float y) {
    float t = 0.7978845608028654f * fmaf(0.044715f, y * y * y, y);
    float e = __expf(2.f * t);
    float th = 1.f - __fdividef(2.f, e + 1.f);
    return 0.5f * y * (1.f + th);
}

// ---------------------------------------------------------------------------
// k_setup: out_w transpose (Wt[h][g] = out_w[g][h]) + out init
// ---------------------------------------------------------------------------
__global__ __launch_bounds__(256) void k_setup(
    const float* __restrict__ out_w, const float* __restrict__ dec_b,
    float* __restrict__ out, float* __restrict__ Wt)
{
    int blk = blockIdx.x, tid = threadIdx.x;
    if (blk < 128) {
        int idx = blk * 256 + tid;            // 0..32767
        int h = idx >> 8, g = idx & 255;
        Wt[idx] = out_w[g * H_ + h];
    } else {
        if (tid < B_) out[tid] = dec_b[0];
    }
}

// ---------------------------------------------------------------------------
// k_s4d: fused encoder + chunked S4D scan + skip + GELU, one block per (b,h).
// thread = chunk c. Phase 1: chunk Horner sums (zero-init states).
// Phase 2: exclusive inter-chunk scan in LDS (Hillis-Steele, weight w^T).
// Phase 3: replay chunk with incoming state, project, GELU, store gy[t*C_+c].
// All global accesses wave-coalesced (lanes <-> consecutive c).
// ---------------------------------------------------------------------------
__global__ __launch_bounds__(128) void k_s4d(
    const float* __restrict__ x, const float* __restrict__ enc_w,
    const float* __restrict__ enc_b, const float* __restrict__ log_dt,
    const float* __restrict__ log_A_real, const float* __restrict__ A_imag,
    const float* __restrict__ C_re, const float* __restrict__ C_im,
    const float* __restrict__ Dp, float* __restrict__ gy)
{
    const int bh = blockIdx.x;
    const int b = bh >> 7, h = bh & (H_ - 1);
    const int c = threadIdx.x;

    __shared__ float4 cw4[N_];        // (wr, wi, coef_r, coef_i)
    __shared__ float2 wT[N_];         // w^T_
    __shared__ float2 S[N_][C_];      // 32 KB scan buffer

    if (c < N_) {
        int idx = h * N_ + c;
        float dt = expf(log_dt[h]);
        float Ar = -expf(log_A_real[idx]);
        float Ai = A_imag[idx];
        float ar = dt * Ar, ai = dt * Ai;
        float er = expf(ar);
        float wr = er * cosf(ai), wi = er * sinf(ai);
        float numr = wr - 1.f, numi = wi;
        float inv = 1.f / (Ar * Ar + Ai * Ai);
        float qr = (numr * Ar + numi * Ai) * inv;
        float qi = (numi * Ar - numr * Ai) * inv;
        cw4[c] = make_float4(wr, wi, C_re[idx] * qr - C_im[idx] * qi,
                                     C_re[idx] * qi + C_im[idx] * qr);
        float erT = expf(ar * (float)T_);
        wT[c] = make_float2(erT * cosf(ai * (float)T_), erT * sinf(ai * (float)T_));
    }
    __syncthreads();

    const float2* xb = (const float2*)x + (size_t)b * L_ + c * T_;
    const float ew0 = enc_w[h], ew1 = enc_w[H_ + h], eb = enc_b[h];

    // ---- Phase 1: E[c] = sum_t w^{T-1-t} u[t], states zero-init ----
    float zr[N_], zi[N_];
#pragma unroll
    for (int n = 0; n < N_; ++n) { zr[n] = 0.f; zi[n] = 0.f; }

    {
        float2 xv[4];
#pragma unroll
        for (int j = 0; j < 4; ++j) xv[j] = xb[j];
#pragma unroll 1
        for (int t4 = 0; t4 < T_ / 4; ++t4) {
            float u[4];
#pragma unroll
            for (int j = 0; j < 4; ++j)
                u[j] = fmaf(xv[j].x, ew0, fmaf(xv[j].y, ew1, eb));
            if (t4 < T_ / 4 - 1) {
#pragma unroll
                for (int j = 0; j < 4; ++j) xv[j] = xb[(t4 + 1) * 4 + j];
            }
#pragma unroll
            for (int n = 0; n < N_; ++n) {
                float4 q = cw4[n];
                float ar_ = zr[n], ai_ = zi[n];
#pragma unroll
                for (int j = 0; j < 4; ++j) {
                    float nr = fmaf(q.x, ar_, fmaf(-q.y, ai_, u[j]));
                    ai_ = fmaf(q.x, ai_, q.y * ar_);
                    ar_ = nr;
                }
                zr[n] = ar_; zi[n] = ai_;
            }
        }
    }

    // ---- Phase 2: exclusive scan over chunks in LDS ----
    // Write E, then shift: z <- E[c-1] (0 for c==0); inclusive Hillis-Steele
    // with weight q_s = (w^T)^(2^s) gives S_in[c].
#pragma unroll
    for (int n = 0; n < N_; ++n) S[n][c] = make_float2(zr[n], zi[n]);
    __syncthreads();
    {
        int cn = (c > 0) ? c - 1 : 0;
        bool has = (c > 0);
#pragma unroll
        for (int n = 0; n < N_; ++n) {
            float2 v = S[n][cn];
            zr[n] = has ? v.x : 0.f;
            zi[n] = has ? v.y : 0.f;
        }
    }
    float qr[N_], qi[N_];
#pragma unroll
    for (int n = 0; n < N_; ++n) { qr[n] = wT[n].x; qi[n] = wT[n].y; }
    __syncthreads();

    for (int s = 1; s < C_; s <<= 1) {
#pragma unroll
        for (int n = 0; n < N_; ++n) S[n][c] = make_float2(zr[n], zi[n]);
        __syncthreads();
        int cn = (c >= s) ? c - s : c;
        bool has = (c >= s);
#pragma unroll
        for (int n = 0; n < N_; ++n) {
            float2 v = S[n][cn];
            float ad_r = fmaf(qr[n], v.x, -(qi[n] * v.y));
            float ad_i = fmaf(qr[n], v.y, qi[n] * v.x);
            zr[n] = has ? zr[n] + ad_r : zr[n];
            zi[n] = has ? zi[n] + ad_i : zi[n];
            float nq = fmaf(qr[n], qr[n], -(qi[n] * qi[n]));
            qi[n] = 2.f * qr[n] * qi[n];
            qr[n] = nq;
        }
        __syncthreads();
    }

    // ---- Phase 3: replay chunk with incoming state; skip+GELU; store ----
    const float Dh = Dp[h];
    float* gyp = gy + (size_t)(b * H_ + h) * L_ + c;
    {
        float2 xv[4];
#pragma unroll
        for (int j = 0; j < 4; ++j) xv[j] = xb[j];
#pragma unroll 1
        for (int t4 = 0; t4 < T_ / 4; ++t4) {
            float u[4], p[4];
#pragma unroll
            for (int j = 0; j < 4; ++j) {
                u[j] = fmaf(xv[j].x, ew0, fmaf(xv[j].y, ew1, eb));
                p[j] = 0.f;
            }
            if (t4 < T_ / 4 - 1) {
#pragma unroll
                for (int j = 0; j < 4; ++j) xv[j] = xb[(t4 + 1) * 4 + j];
            }
#pragma unroll
            for (int n = 0; n < N_; ++n) {
                float4 q = cw4[n];
                float ar_ = zr[n], ai_ = zi[n];
#pragma unroll
                for (int j = 0; j < 4; ++j) {
                    float nr = fmaf(q.x, ar_, fmaf(-q.y, ai_, u[j]));
                    ai_ = fmaf(q.x, ai_, q.y * ar_);
                    ar_ = nr;
                    p[j] = fmaf(q.z, ar_, fmaf(-q.w, ai_, p[j]));
                }
                zr[n] = ar_; zi[n] = ai_;
            }
#pragma unroll
            for (int j = 0; j < 4; ++j) {
                float y = fmaf(Dh, u[j], 2.f * p[j]);
                gyp[(size_t)(t4 * 4 + j) * C_] = gelu_tanh(y);
            }
        }
    }
}

// ---------------------------------------------------------------------------
// k_mix: pointwise GLU mix + pooled decode (order-invariant over l).
// ---------------------------------------------------------------------------
__global__ __launch_bounds__(256) void k_mix(
    const float* __restrict__ Wt, const float* __restrict__ gy,
    const float* __restrict__ out_b, const float* __restrict__ dec_w,
    float* __restrict__ out)
{
    __shared__ float Wl[32][256];
    __shared__ float red[4];
    int blk = blockIdx.x;
    int b = blk >> 7, lt = blk & 127;
    int l0 = lt * 64;
    int tid = threadIdx.x;
    int wq = tid >> 6, lane = tid & 63;
    int g0 = wq * 32;

    float aa[32], ag[32];
#pragma unroll
    for (int j = 0; j < 32; ++j) { aa[j] = 0.f; ag[j] = 0.f; }

    for (int hc = 0; hc < 4; ++hc) {
        __syncthreads();
        const float4* src = (const float4*)(Wt + hc * 32 * 256);
        float4* dst = (float4*)(&Wl[0][0]);
#pragma unroll
        for (int r = 0; r < 8; ++r) dst[r * 256 + tid] = src[r * 256 + tid];
        __syncthreads();
        const float* gp = gy + (b * H_ + hc * 32) * L_ + l0 + lane;
#pragma unroll 2
        for (int h = 0; h < 32; ++h) {
            float v = gp[(size_t)h * L_];
#pragma unroll
            for (int j4 = 0; j4 < 8; ++j4) {
                float4 wa = *(const float4*)&Wl[h][g0 + j4 * 4];
                float4 wg = *(const float4*)&Wl[h][128 + g0 + j4 * 4];
                aa[j4 * 4 + 0] = fmaf(wa.x, v, aa[j4 * 4 + 0]);
                aa[j4 * 4 + 1] = fmaf(wa.y, v, aa[j4 * 4 + 1]);
                aa[j4 * 4 + 2] = fmaf(wa.z, v, aa[j4 * 4 + 2]);
                aa[j4 * 4 + 3] = fmaf(wa.w, v, aa[j4 * 4 + 3]);
                ag[j4 * 4 + 0] = fmaf(wg.x, v, ag[j4 * 4 + 0]);
                ag[j4 * 4 + 1] = fmaf(wg.y, v, ag[j4 * 4 + 1]);
                ag[j4 * 4 + 2] = fmaf(wg.z, v, ag[j4 * 4 + 2]);
                ag[j4 * 4 + 3] = fmaf(wg.w, v, ag[j4 * 4 + 3]);
            }
        }
    }
    float s = 0.f;
#pragma unroll
    for (int j = 0; j < 32; ++j) {
        int g = g0 + j;
        float za = aa[j] + out_b[g];
        float zg = ag[j] + out_b[128 + g];
        float sig = __fdividef(1.f, 1.f + __expf(-zg));
        s = fmaf(dec_w[g], za * sig, s);
    }
#pragma unroll
    for (int off = 32; off; off >>= 1) s += __shfl_down(s, off, 64);
    if (lane == 0) red[wq] = s;
    __syncthreads();
    if (tid == 0) {
        float tot = (red[0] + red[1] + red[2] + red[3]) * (1.0f / (float)L_);
        atomicAdd(out + b, tot);
    }
}

// ---------------------------------------------------------------------------
extern "C" void kernel_launch(void* const* d_in, const int* in_sizes, int n_in,
                              void* d_out, int out_size, void* d_ws, size_t ws_size,
                              hipStream_t stream)
{
    const float* x         = (const float*)d_in[0];
    const float* enc_w     = (const float*)d_in[1];
    const float* enc_b     = (const float*)d_in[2];
    const float* log_dt    = (const float*)d_in[3];
    const float* log_A_real= (const float*)d_in[4];
    const float* A_imag    = (const float*)d_in[5];
    const float* C_re      = (const float*)d_in[6];
    const float* C_im      = (const float*)d_in[7];
    const float* Dp        = (const float*)d_in[8];
    const float* out_w     = (const float*)d_in[9];
    const float* out_b     = (const float*)d_in[10];
    const float* dec_w     = (const float*)d_in[11];
    const float* dec_b     = (const float*)d_in[12];
    float* out = (float*)d_out;

    char* ws = (char*)d_ws;
    float* Wt = (float*)(ws);
    float* gy = (float*)(ws + 131072);

    k_setup<<<129, 256, 0, stream>>>(out_w, dec_b, out, Wt);
    k_s4d<<<B_ * H_, C_, 0, stream>>>(x, enc_w, enc_b, log_dt, log_A_real,
                                      A_imag, C_re, C_im, Dp, gy);
    k_mix<<<B_ * 128, 256, 0, stream>>>(Wt, gy, out_b, dec_w, out);
}